// Round 10
// baseline (112.924 us; speedup 1.0000x reference)
//
#include <hip/hip_runtime.h>

// DIAGNOSTIC ROUND (R10): R8/R9 proved structure-insensitivity (82.1 vs 82.6)
// but our kernel never appears in rocprof top-5 (faster than the 43-45us
// harness fills). This build repeats the main body 4x (idempotent rewrites,
// memory-clobber per rep to defeat hoisting) so the kernel becomes the #1
// dispatch and we finally read ITS counters. dur_us ~= 56 + 4K: K=13 -> ~115,
// K=25 -> ~160. WRITE_SIZE/hbm_gbps of the kernel row resolves write efficiency.

#define DD 32
#define BT 128
#define REPS 4

typedef __attribute__((ext_vector_type(8))) short bfrag8;
typedef __attribute__((ext_vector_type(4))) float f32x4;

__device__ __forceinline__ unsigned short f2bf_rn(float f) {
    unsigned u = __builtin_bit_cast(unsigned, f);
    u += 0x7FFFu + ((u >> 16) & 1u);      // RNE (inputs finite)
    return (unsigned short)(u >> 16);
}
__device__ __forceinline__ float bf2f(unsigned short h) {
    unsigned u = ((unsigned)h) << 16;
    return __builtin_bit_cast(float, u);
}

// ---- pre-kernel: one row per thread; f32 -> (hi,lo) bf16 + negated half-norm ----
__global__ __launch_bounds__(64) void rbf_pre_kernel(
    const float* __restrict__ A, const float* __restrict__ B,
    unsigned short* __restrict__ ah, unsigned short* __restrict__ al,
    unsigned short* __restrict__ bh, unsigned short* __restrict__ bl,
    float* __restrict__ nhA, float* __restrict__ nhB, int N)
{
    const int r   = blockIdx.x * 64 + threadIdx.x;
    const bool isB = r >= N;
    const int row = isB ? r - N : r;
    const float4* src = reinterpret_cast<const float4*>((isB ? B : A) + (size_t)row * DD);
    unsigned short* dh = (isB ? bh : ah) + (size_t)row * DD;
    unsigned short* dl = (isB ? bl : al) + (size_t)row * DD;
    float s = 0.f;
    #pragma unroll
    for (int q = 0; q < 8; ++q) {
        float4 v = src[q];
        s += v.x * v.x + v.y * v.y + v.z * v.z + v.w * v.w;
        ushort4 h, l;
        h.x = f2bf_rn(v.x); l.x = f2bf_rn(v.x - bf2f(h.x));
        h.y = f2bf_rn(v.y); l.y = f2bf_rn(v.y - bf2f(h.y));
        h.z = f2bf_rn(v.z); l.z = f2bf_rn(v.z - bf2f(h.z));
        h.w = f2bf_rn(v.w); l.w = f2bf_rn(v.w - bf2f(h.w));
        *reinterpret_cast<ushort4*>(dh + q * 4) = h;
        *reinterpret_cast<ushort4*>(dl + q * 4) = l;
    }
    ((isB ? nhB : nhA))[row] = -0.5f * s;
}

// ---- main: body repeated REPS times (idempotent) for counter visibility ----
__global__ __launch_bounds__(256, 4) void rbf_mfma4_kernel(
    const unsigned short* __restrict__ ah, const unsigned short* __restrict__ al,
    const unsigned short* __restrict__ bh, const unsigned short* __restrict__ bl,
    const float* __restrict__ nhA, const float* __restrict__ nhB,
    float* __restrict__ out, int M)
{
    const int tid  = threadIdx.x;
    const int brow = blockIdx.y * BT;
    const int bcol = blockIdx.x * BT;
    const int lane = tid & 63, wid = tid >> 6;
    const int r0 = wid * 32;
    const int lr = lane & 15;
    const int lg = lane >> 4;
    const int k0 = lg * 8;

    #pragma unroll 1
    for (int rep = 0; rep < REPS; ++rep) {
        asm volatile("" ::: "memory");   // force re-load/re-compute each rep

        const size_t arow = (size_t)(brow + r0 + lr) * DD + k0;
        const bfrag8 ah0 = *reinterpret_cast<const bfrag8*>(ah + arow);
        const bfrag8 al0 = *reinterpret_cast<const bfrag8*>(al + arow);
        const bfrag8 ah1 = *reinterpret_cast<const bfrag8*>(ah + arow + (size_t)16 * DD);
        const bfrag8 al1 = *reinterpret_cast<const bfrag8*>(al + arow + (size_t)16 * DD);

        float nha0[4], nha1[4];
        #pragma unroll
        for (int q = 0; q < 4; ++q) {
            nha0[q] = nhA[brow + r0 + lg * 4 + q];
            nha1[q] = nhA[brow + r0 + 16 + lg * 4 + q];
        }

        const size_t orow0 = (size_t)(brow + r0 + lg * 4) * M + bcol;

        #pragma unroll 2
        for (int c = 0; c < 8; ++c) {
            const int c0 = c * 16;
            const size_t brow_off = (size_t)(bcol + c0 + lr) * DD + k0;
            const bfrag8 bhf = *reinterpret_cast<const bfrag8*>(bh + brow_off);
            const bfrag8 blf = *reinterpret_cast<const bfrag8*>(bl + brow_off);
            const float nhb = nhB[bcol + c0 + lr];

            f32x4 acc0 = {0.f, 0.f, 0.f, 0.f}, acc1 = {0.f, 0.f, 0.f, 0.f};
            acc0 = __builtin_amdgcn_mfma_f32_16x16x32_bf16(al0, bhf, acc0, 0, 0, 0);
            acc1 = __builtin_amdgcn_mfma_f32_16x16x32_bf16(al1, bhf, acc1, 0, 0, 0);
            acc0 = __builtin_amdgcn_mfma_f32_16x16x32_bf16(ah0, blf, acc0, 0, 0, 0);
            acc1 = __builtin_amdgcn_mfma_f32_16x16x32_bf16(ah1, blf, acc1, 0, 0, 0);
            acc0 = __builtin_amdgcn_mfma_f32_16x16x32_bf16(ah0, bhf, acc0, 0, 0, 0);
            acc1 = __builtin_amdgcn_mfma_f32_16x16x32_bf16(ah1, bhf, acc1, 0, 0, 0);

            float* p0 = out + orow0 + c0 + lr;
            #pragma unroll
            for (int q = 0; q < 4; ++q) {
                p0[(size_t)q * M]        = __expf(acc0[q] + nha0[q] + nhb);
                p0[(size_t)(q + 16) * M] = __expf(acc1[q] + nha1[q] + nhb);
            }
        }
    }
}

extern "C" void kernel_launch(void* const* d_in, const int* in_sizes, int n_in,
                              void* d_out, int out_size, void* d_ws, size_t ws_size,
                              hipStream_t stream) {
    const float* A = (const float*)d_in[0];
    const float* B = (const float*)d_in[1];
    float* out     = (float*)d_out;
    const int N = in_sizes[0] / DD;   // 4096
    const int M = in_sizes[1] / DD;   // 4096

    char* ws = (char*)d_ws;
    unsigned short* ah = (unsigned short*)(ws);
    unsigned short* al = (unsigned short*)(ws + 0x40000);
    unsigned short* bh = (unsigned short*)(ws + 0x80000);
    unsigned short* bl = (unsigned short*)(ws + 0xC0000);
    float* nhA = (float*)(ws + 0x100000);
    float* nhB = (float*)(ws + 0x104000);

    rbf_pre_kernel<<<(N + M) / 64, 64, 0, stream>>>(A, B, ah, al, bh, bl, nhA, nhB, N);
    dim3 grid(M / BT, N / BT);        // 32 x 32 = 1024 blocks
    rbf_mfma4_kernel<<<grid, 256, 0, stream>>>(ah, al, bh, bl, nhA, nhB, out, M);
}

// Round 11
// 81.583 us; speedup vs baseline: 1.3841x; 1.3841x over previous
//
#include <hip/hip_runtime.h>

// out[n,m] = exp(i1[n]·i2[m] - ||i1[n]||^2/2 - ||i2[m]||^2/2), N=M=4096, D=32, f32.
// R10 diagnostic (4x-rep) measured the main kernel at 11.2us/rep, 6.2 TB/s HBM
// write (78% spec peak = 99% of 6.3 TB/s achievable; harness's own fills run
// 74-77%). WRITE_SIZE exact (no RMW), bank conflicts 0, compute hidden
// (MfmaUtil 10%, VALUBusy 25%). Kernel is AT the write roofline.
// This build: revert diagnostic -> best measured 1x structure (R8 fused, 82.1us;
// dur_us = ~56us harness re-poison fills + ~11us kernel + ~15us fixed slack).

#define DD 32
#define BT 128
#define KP 40   // ushort row stride: 32 bf16 data + pad; f32 half-norm at slots 32..33

typedef __attribute__((ext_vector_type(8))) short bfrag8;
typedef __attribute__((ext_vector_type(4))) float f32x4;

__device__ __forceinline__ unsigned short f2bf_rn(float f) {
    unsigned u = __builtin_bit_cast(unsigned, f);
    u += 0x7FFFu + ((u >> 16) & 1u);      // round-to-nearest-even (inputs are finite)
    return (unsigned short)(u >> 16);
}
__device__ __forceinline__ float bf2f(unsigned short h) {
    unsigned u = ((unsigned)h) << 16;
    return __builtin_bit_cast(float, u);
}

__global__ __launch_bounds__(256) void rbf_mfma_kernel(
    const float* __restrict__ A,   // [N][32]
    const float* __restrict__ B,   // [M][32]
    float* __restrict__ out,       // [N][M]
    int M)
{
    __shared__ unsigned short sAh[BT][KP];   // 4 x 10 KB = 40 KB total -> 4 blocks/CU
    __shared__ unsigned short sAl[BT][KP];
    __shared__ unsigned short sBh[BT][KP];
    __shared__ unsigned short sBl[BT][KP];

    const int tid  = threadIdx.x;
    const int brow = blockIdx.y * BT;
    const int bcol = blockIdx.x * BT;

    const float4* gA = reinterpret_cast<const float4*>(A + (size_t)brow * DD);
    const float4* gB = reinterpret_cast<const float4*>(B + (size_t)bcol * DD);

    // ---- stage: f32 -> (hi,lo) bf16 split into LDS, row-major [row][d] ----
    #pragma unroll
    for (int k = 0; k < 4; ++k) {
        const int i   = tid + k * 256;   // 0..1023
        const int row = i >> 3;
        const int d0  = (i & 7) << 2;
        float4 va = gA[i], vb = gB[i];
        ushort4 ha, la, hb, lb;
        ha.x = f2bf_rn(va.x); la.x = f2bf_rn(va.x - bf2f(ha.x));
        ha.y = f2bf_rn(va.y); la.y = f2bf_rn(va.y - bf2f(ha.y));
        ha.z = f2bf_rn(va.z); la.z = f2bf_rn(va.z - bf2f(ha.z));
        ha.w = f2bf_rn(va.w); la.w = f2bf_rn(va.w - bf2f(ha.w));
        hb.x = f2bf_rn(vb.x); lb.x = f2bf_rn(vb.x - bf2f(hb.x));
        hb.y = f2bf_rn(vb.y); lb.y = f2bf_rn(vb.y - bf2f(hb.y));
        hb.z = f2bf_rn(vb.z); lb.z = f2bf_rn(vb.z - bf2f(hb.z));
        hb.w = f2bf_rn(vb.w); lb.w = f2bf_rn(vb.w - bf2f(hb.w));
        *reinterpret_cast<ushort4*>(&sAh[row][d0]) = ha;
        *reinterpret_cast<ushort4*>(&sAl[row][d0]) = la;
        *reinterpret_cast<ushort4*>(&sBh[row][d0]) = hb;
        *reinterpret_cast<ushort4*>(&sBl[row][d0]) = lb;
    }

    // ---- f32 half-norms from global (L1-hot), stashed in the row pad ----
    {
        const int r = tid & 127;
        const float4* src = (tid < 128)
            ? reinterpret_cast<const float4*>(A + (size_t)(brow + r) * DD)
            : reinterpret_cast<const float4*>(B + (size_t)(bcol + r) * DD);
        float s = 0.f;
        #pragma unroll
        for (int q = 0; q < 8; ++q) {
            float4 v = src[q];
            s += v.x * v.x + v.y * v.y + v.z * v.z + v.w * v.w;
        }
        unsigned short* dst = (tid < 128) ? &sAh[r][32] : &sBh[r][32];
        *reinterpret_cast<float*>(dst) = 0.5f * s;   // disjoint bytes vs staged data
    }
    __syncthreads();

    // ---- per-wave MFMA: wave w owns rows [w*32, w*32+32), all 128 cols ----
    const int lane = tid & 63, wid = tid >> 6;
    const int r0 = wid * 32;
    const int lr = lane & 15;        // A-frag row / B-frag col / D col
    const int lg = lane >> 4;        // k-group; D row group
    const int k0 = lg * 8;

    const bfrag8 ah0 = *reinterpret_cast<const bfrag8*>(&sAh[r0 + lr][k0]);
    const bfrag8 al0 = *reinterpret_cast<const bfrag8*>(&sAl[r0 + lr][k0]);
    const bfrag8 ah1 = *reinterpret_cast<const bfrag8*>(&sAh[r0 + 16 + lr][k0]);
    const bfrag8 al1 = *reinterpret_cast<const bfrag8*>(&sAl[r0 + 16 + lr][k0]);

    float hna0[4], hna1[4];
    #pragma unroll
    for (int q = 0; q < 4; ++q) {
        hna0[q] = *reinterpret_cast<const float*>(&sAh[r0 + lg * 4 + q][32]);
        hna1[q] = *reinterpret_cast<const float*>(&sAh[r0 + 16 + lg * 4 + q][32]);
    }

    const size_t orow0 = (size_t)(brow + r0 + lg * 4) * M + bcol;

    #pragma unroll
    for (int c = 0; c < 8; ++c) {
        const int c0 = c * 16;
        const bfrag8 bh = *reinterpret_cast<const bfrag8*>(&sBh[c0 + lr][k0]);
        const bfrag8 bl = *reinterpret_cast<const bfrag8*>(&sBl[c0 + lr][k0]);
        const float hnb = *reinterpret_cast<const float*>(&sBh[c0 + lr][32]);

        f32x4 acc0 = {0.f, 0.f, 0.f, 0.f}, acc1 = {0.f, 0.f, 0.f, 0.f};
        acc0 = __builtin_amdgcn_mfma_f32_16x16x32_bf16(al0, bh, acc0, 0, 0, 0);
        acc1 = __builtin_amdgcn_mfma_f32_16x16x32_bf16(al1, bh, acc1, 0, 0, 0);
        acc0 = __builtin_amdgcn_mfma_f32_16x16x32_bf16(ah0, bl, acc0, 0, 0, 0);
        acc1 = __builtin_amdgcn_mfma_f32_16x16x32_bf16(ah1, bl, acc1, 0, 0, 0);
        acc0 = __builtin_amdgcn_mfma_f32_16x16x32_bf16(ah0, bh, acc0, 0, 0, 0);
        acc1 = __builtin_amdgcn_mfma_f32_16x16x32_bf16(ah1, bh, acc1, 0, 0, 0);

        float* p0 = out + orow0 + c0 + lr;   // D: col = lane&15, row = lg*4 + q
        #pragma unroll
        for (int q = 0; q < 4; ++q) {
            p0[(size_t)q * M]        = __expf(acc0[q] - hna0[q] - hnb);
            p0[(size_t)(q + 16) * M] = __expf(acc1[q] - hna1[q] - hnb);
        }
    }
}

extern "C" void kernel_launch(void* const* d_in, const int* in_sizes, int n_in,
                              void* d_out, int out_size, void* d_ws, size_t ws_size,
                              hipStream_t stream) {
    const float* A = (const float*)d_in[0];
    const float* B = (const float*)d_in[1];
    float* out     = (float*)d_out;
    const int N = in_sizes[0] / DD;   // 4096
    const int M = in_sizes[1] / DD;   // 4096
    dim3 grid(M / BT, N / BT);        // 32 x 32 = 1024 blocks -> 4/CU, single round
    rbf_mfma_kernel<<<grid, 256, 0, stream>>>(A, B, out, M);
}